// Round 8
// baseline (305.563 us; speedup 1.0000x reference)
//
#include <hip/hip_runtime.h>
#include <hip/hip_bf16.h>
#include <stdint.h>
#include <math.h>

#define B_ 4
#define T_ 2048
#define E_ 1024
#define H_ 16
#define D_ 64

typedef __attribute__((ext_vector_type(8))) short short8;
typedef __attribute__((ext_vector_type(4))) float f32x4;

#define MFMA_BF16(a, b, c) __builtin_amdgcn_mfma_f32_16x16x32_bf16((a), (b), (c), 0, 0, 0)

__device__ __forceinline__ unsigned short f2bf(float f) {
  union { float f; unsigned u; } v; v.f = f;
  unsigned r = v.u + 0x7FFFu + ((v.u >> 16) & 1u);  // RNE
  return (unsigned short)(r >> 16);
}

#define GLOAD_LDS16(g, l)                                                        \
  __builtin_amdgcn_global_load_lds((const __attribute__((address_space(1))) void*)(g), \
                                   (__attribute__((address_space(3))) void*)(l), 16, 0, 0)

// ---------------- fp32 -> bf16 convert (vectorized) ----------------
__global__ __launch_bounds__(256) void cvt_f32_bf16(const float* __restrict__ in,
                                                    unsigned short* __restrict__ out,
                                                    int n8) {
  int i = blockIdx.x * blockDim.x + threadIdx.x;
  if (i >= n8) return;
  const float4* p = (const float4*)(in + (size_t)i * 8);
  float4 a = p[0], b = p[1];
  short8 r;
  r[0] = (short)f2bf(a.x); r[1] = (short)f2bf(a.y);
  r[2] = (short)f2bf(a.z); r[3] = (short)f2bf(a.w);
  r[4] = (short)f2bf(b.x); r[5] = (short)f2bf(b.y);
  r[6] = (short)f2bf(b.z); r[7] = (short)f2bf(b.w);
  *(short8*)(out + (size_t)i * 8) = r;
}

// 4 weight matrices in one launch (dest regions contiguous in ws)
__global__ __launch_bounds__(256) void cvt_w4(const float* __restrict__ w0,
                                              const float* __restrict__ w1,
                                              const float* __restrict__ w2,
                                              const float* __restrict__ w3,
                                              unsigned short* __restrict__ out) {
  int i = blockIdx.x * blockDim.x + threadIdx.x;  // one per 8 elems
  int which = i >> 17;                            // WE/8 = 2^17
  int off = i & 131071;
  const float* src = (which == 0) ? w0 : (which == 1) ? w1 : (which == 2) ? w2 : w3;
  const float4* p = (const float4*)(src + (size_t)off * 8);
  float4 a = p[0], b = p[1];
  short8 r;
  r[0] = (short)f2bf(a.x); r[1] = (short)f2bf(a.y);
  r[2] = (short)f2bf(a.z); r[3] = (short)f2bf(a.w);
  r[4] = (short)f2bf(b.x); r[5] = (short)f2bf(b.y);
  r[6] = (short)f2bf(b.z); r[7] = (short)f2bf(b.w);
  *(short8*)(out + ((size_t)which << 20) + (size_t)off * 8) = r;
}

// ---------------- fused QKV GEMM: C = x * W^T for W in {Wq,Wk,Wv} -------------
__global__ __launch_bounds__(256) void gemm_qkv(const unsigned short* __restrict__ A,
                                                const unsigned short* __restrict__ Wq,
                                                const unsigned short* __restrict__ Wk,
                                                const unsigned short* __restrict__ Wv,
                                                unsigned short* __restrict__ Qo,
                                                unsigned short* __restrict__ Ko,
                                                unsigned short* __restrict__ Vo) {
  __shared__ __align__(16) unsigned short Ab[128 * 64];
  __shared__ __align__(16) unsigned short Bb[128 * 64];
  const int K = E_;
  const int tid = threadIdx.x;
  const int wid = tid >> 6;
  const int lr = tid & 15;
  const int lk = (tid >> 4) & 3;
  const int wr = wid >> 1, wc = wid & 1;
  const int m0 = blockIdx.x * 128;
  const int sel = blockIdx.y >> 3;
  const int n0 = (blockIdx.y & 7) * 128;
  const unsigned short* Bm = (sel == 0) ? Wq : (sel == 1) ? Wk : Wv;
  unsigned short* outp = (sel == 0) ? Qo : (sel == 1) ? Ko : Vo;

  f32x4 acc[4][4] = {};

  for (int k0 = 0; k0 < K; k0 += 64) {
    __syncthreads();
#pragma unroll
    for (int pass = 0; pass < 4; ++pass) {
      int chunk = pass * 256 + tid;
      int row = chunk >> 3, inner = chunk & 7;
      const unsigned short* ga = A + (size_t)(m0 + row) * K + k0 + inner * 8;
      const unsigned short* gb = Bm + (size_t)(n0 + row) * K + k0 + inner * 8;
      unsigned short* la = Ab + (size_t)(pass * 256 + wid * 64) * 8;
      unsigned short* lb = Bb + (size_t)(pass * 256 + wid * 64) * 8;
      GLOAD_LDS16(ga, la);
      GLOAD_LDS16(gb, lb);
    }
    __syncthreads();
#pragma unroll
    for (int kk = 0; kk < 2; ++kk) {
      short8 af[4], bf[4];
#pragma unroll
      for (int mi = 0; mi < 4; ++mi)
        af[mi] = *(const short8*)&Ab[(wr * 64 + mi * 16 + lr) * 64 + kk * 32 + lk * 8];
#pragma unroll
      for (int ni = 0; ni < 4; ++ni)
        bf[ni] = *(const short8*)&Bb[(wc * 64 + ni * 16 + lr) * 64 + kk * 32 + lk * 8];
#pragma unroll
      for (int mi = 0; mi < 4; ++mi)
#pragma unroll
        for (int ni = 0; ni < 4; ++ni)
          acc[mi][ni] = MFMA_BF16(af[mi], bf[ni], acc[mi][ni]);
    }
  }

#pragma unroll
  for (int mi = 0; mi < 4; ++mi)
#pragma unroll
    for (int ni = 0; ni < 4; ++ni)
#pragma unroll
      for (int r = 0; r < 4; ++r) {
        int row = m0 + wr * 64 + mi * 16 + lk * 4 + r;
        int col = n0 + wc * 64 + ni * 16 + lr;
        int b = row >> 11, t = row & (T_ - 1), h = col >> 6, d = col & (D_ - 1);
        outp[(((size_t)(b * H_ + h)) * T_ + t) * D_ + d] = f2bf(acc[mi][ni][r]);
      }
}

// ---------------- out-proj GEMM: fp32 out + bias ----------------
__global__ __launch_bounds__(256) void gemm_out(const unsigned short* __restrict__ A,
                                                const unsigned short* __restrict__ Bm,
                                                float* __restrict__ outp,
                                                const float* __restrict__ bias,
                                                int M, int N, int K) {
  __shared__ __align__(16) unsigned short Ab[128 * 64];
  __shared__ __align__(16) unsigned short Bb[128 * 64];
  const int tid = threadIdx.x;
  const int wid = tid >> 6;
  const int lr = tid & 15;
  const int lk = (tid >> 4) & 3;
  const int wr = wid >> 1, wc = wid & 1;
  const int m0 = blockIdx.x * 128, n0 = blockIdx.y * 128;

  f32x4 acc[4][4] = {};

  for (int k0 = 0; k0 < K; k0 += 64) {
    __syncthreads();
#pragma unroll
    for (int pass = 0; pass < 4; ++pass) {
      int chunk = pass * 256 + tid;
      int row = chunk >> 3, inner = chunk & 7;
      const unsigned short* ga = A + (size_t)(m0 + row) * K + k0 + inner * 8;
      const unsigned short* gb = Bm + (size_t)(n0 + row) * K + k0 + inner * 8;
      unsigned short* la = Ab + (size_t)(pass * 256 + wid * 64) * 8;
      unsigned short* lb = Bb + (size_t)(pass * 256 + wid * 64) * 8;
      GLOAD_LDS16(ga, la);
      GLOAD_LDS16(gb, lb);
    }
    __syncthreads();
#pragma unroll
    for (int kk = 0; kk < 2; ++kk) {
      short8 af[4], bf[4];
#pragma unroll
      for (int mi = 0; mi < 4; ++mi)
        af[mi] = *(const short8*)&Ab[(wr * 64 + mi * 16 + lr) * 64 + kk * 32 + lk * 8];
#pragma unroll
      for (int ni = 0; ni < 4; ++ni)
        bf[ni] = *(const short8*)&Bb[(wc * 64 + ni * 16 + lr) * 64 + kk * 32 + lk * 8];
#pragma unroll
      for (int mi = 0; mi < 4; ++mi)
#pragma unroll
        for (int ni = 0; ni < 4; ++ni)
          acc[mi][ni] = MFMA_BF16(af[mi], bf[ni], acc[mi][ni]);
    }
  }

#pragma unroll
  for (int mi = 0; mi < 4; ++mi)
#pragma unroll
    for (int ni = 0; ni < 4; ++ni)
#pragma unroll
      for (int r = 0; r < 4; ++r) {
        int row = m0 + wr * 64 + mi * 16 + lk * 4 + r;
        int col = n0 + wc * 64 + ni * 16 + lr;
        outp[(size_t)row * N + col] = acc[mi][ni][r] + bias[col];
      }
}

// ---------------- V transpose: [BH][T][D] -> [BH][D][T] ----------------
__global__ __launch_bounds__(256) void transpose_v(const unsigned short* __restrict__ V,
                                                   unsigned short* __restrict__ VT) {
  const int lane = threadIdx.x & 63;
  const int w = threadIdx.x >> 6;
  const int tb = blockIdx.x * 64;
  const int bh = blockIdx.y;
  const unsigned short* Vh = V + (size_t)bh * T_ * D_;
  unsigned short* Vo = VT + (size_t)bh * T_ * D_;
  short8 v0, v1;
#pragma unroll
  for (int j = 0; j < 8; ++j)
    v0[j] = (short)Vh[(size_t)(tb + w * 16 + j) * D_ + lane];
#pragma unroll
  for (int j = 0; j < 8; ++j)
    v1[j] = (short)Vh[(size_t)(tb + w * 16 + 8 + j) * D_ + lane];
  *(short8*)&Vo[(size_t)lane * T_ + tb + w * 16] = v0;
  *(short8*)&Vo[(size_t)lane * T_ + tb + w * 16 + 8] = v1;
}

// ---------------- fused causal flash attention (split-KV, 4-wave merge) ------
// 4096 blocks x 256 thr. Block = one 32-row q-chunk of one head; wave w
// handles kv-tiles {w, w+4, ...} with private (m, l, O) — SAME total K/V
// load volume as the 1-wave version, but 4x resident parallelism per CU.
// Flash-merge at the end: m* = max_w m_w; O = sum_w 2^(m_w-m*) O_w; same for l.
__global__ __launch_bounds__(256, 4) void attn_fused(const unsigned short* __restrict__ Q,
                                                     const unsigned short* __restrict__ K,
                                                     const unsigned short* __restrict__ VT,
                                                     unsigned short* __restrict__ ctx) {
  __shared__ __align__(16) unsigned short Pl[4 * 32 * 72];  // per-wave P, stride 144B
  __shared__ __align__(16) float Om[64][36];                // [col=d][row=q], pad->conflict-free b128
  __shared__ float Lm[4][2][16];                            // per-wave m, [w][a][q&15]
  __shared__ float Lf[2][16];                               // merged l
  const int tid = threadIdx.x;
  const int wid = tid >> 6;
  const int lane = tid & 63;
  const int lr = lane & 15;
  const int lk = lane >> 4;

  // XCD swizzle: 8 heads/XCD; heaviest chunks dispatched first.
  const int bid = blockIdx.x;
  const int xcd = bid & 7;
  const int p = bid >> 3;           // 0..511 per XCD
  const int bh = xcd * 8 + (p & 7);
  const int chunk = 63 - (p >> 3);  // heavy first
  const int q0 = chunk * 32;

  const unsigned short* Qh = Q + (size_t)bh * T_ * D_;
  const unsigned short* Kh = K + (size_t)bh * T_ * D_;
  const unsigned short* Vh = VT + (size_t)bh * T_ * D_;  // [D][T]
  char* Pb = (char*)Pl + wid * 4608;

  const float SC = 0.125f * 1.44269504089f;  // 1/sqrt(D) * log2(e)

  short8 vones;
#pragma unroll
  for (int j = 0; j < 8; ++j) vones[j] = (short)0x3F80;  // bf16 1.0

  // Q as B-operand: col=q=lr, k=d
  short8 qf[2][2];
#pragma unroll
  for (int a = 0; a < 2; ++a)
#pragma unroll
    for (int kb = 0; kb < 2; ++kb)
      qf[a][kb] = *(const short8*)&Qh[(size_t)(q0 + a * 16 + lr) * D_ + kb * 32 + lk * 8];

  f32x4 o[2][4] = {};
  f32x4 lsum[2] = {};
  float mrun[2] = {-1e30f, -1e30f};

  const int nt = (q0 >> 6) + 1;
  const int ql0 = q0 & 63;  // q-local base within diag tile

  for (int kvt = wid; kvt < nt; kvt += 4) {
    const unsigned short* Kt = Kh + (size_t)kvt * 64 * D_;
    const unsigned short* Vtt = Vh + (size_t)kvt * 64;

    // K fragments (QK waits on these)
    short8 kf[2][4];
#pragma unroll
    for (int kb = 0; kb < 2; ++kb)
#pragma unroll
      for (int n = 0; n < 4; ++n)
        kf[kb][n] = *(const short8*)&Kt[(size_t)(n * 16 + lr) * D_ + kb * 32 + lk * 8];

    // V fragments (latency hidden under softmax)
    short8 vreg[2][4];
#pragma unroll
    for (int kb = 0; kb < 2; ++kb)
#pragma unroll
      for (int nd = 0; nd < 4; ++nd)
        vreg[kb][nd] = *(const short8*)&Vtt[(size_t)(nd * 16 + lr) * T_ + kb * 32 + lk * 8];

    // S^T = K Q^T : row=kv (n*16+lk*4+r), col=q (lr)
    f32x4 st[2][4] = {};
#pragma unroll
    for (int kb = 0; kb < 2; ++kb)
#pragma unroll
      for (int a = 0; a < 2; ++a)
#pragma unroll
        for (int n = 0; n < 4; ++n)
          st[a][n] = MFMA_BF16(kf[kb][n], qf[a][kb], st[a][n]);

    if (kvt == nt - 1) {  // diagonal tile: mask kv_local > q_local
#pragma unroll
      for (int a = 0; a < 2; ++a)
#pragma unroll
        for (int n = 0; n < 4; ++n)
#pragma unroll
          for (int r = 0; r < 4; ++r)
            if (n * 16 + lk * 4 + r > ql0 + a * 16 + lr) st[a][n][r] = -3e38f;
    }

    // row max (in-lane tree + 2 shuffles)
    float pm[2];
#pragma unroll
    for (int a = 0; a < 2; ++a) {
      float m0 = fmaxf(fmaxf(st[a][0][0], st[a][1][0]), fmaxf(st[a][2][0], st[a][3][0]));
      float m1 = fmaxf(fmaxf(st[a][0][1], st[a][1][1]), fmaxf(st[a][2][1], st[a][3][1]));
      float m2 = fmaxf(fmaxf(st[a][0][2], st[a][1][2]), fmaxf(st[a][2][2], st[a][3][2]));
      float m3 = fmaxf(fmaxf(st[a][0][3], st[a][1][3]), fmaxf(st[a][2][3], st[a][3][3]));
      float mx = fmaxf(fmaxf(m0, m1), fmaxf(m2, m3));
      mx = fmaxf(mx, __shfl_xor(mx, 16));
      mx = fmaxf(mx, __shfl_xor(mx, 32));
      pm[a] = mx * SC;
    }
    float need = fmaxf(pm[0] - mrun[0], pm[1] - mrun[1]);

    if (__any(need > 8.f)) {  // defer-max rescale (rare)
#pragma unroll
      for (int a = 0; a < 2; ++a) {
        float mnew = fmaxf(mrun[a], pm[a]);
        float sc = exp2f(mrun[a] - mnew);
        mrun[a] = mnew;
#pragma unroll
        for (int r = 0; r < 4; ++r) {
          float sco = __shfl(sc, (lane & 48) | (lk * 4 + r));
          lsum[a][r] *= sco;
#pragma unroll
          for (int nd = 0; nd < 4; ++nd) o[a][nd][r] *= sco;
        }
      }
    }

    // P = exp2(S*SC - m), packed bf16x4 -> per-wave LDS (8x ds_write_b64)
#pragma unroll
    for (int a = 0; a < 2; ++a)
#pragma unroll
      for (int n = 0; n < 4; ++n) {
        float2 p01, p23;
        p01.x = exp2f(fmaf(st[a][n][0], SC, -mrun[a]));
        p01.y = exp2f(fmaf(st[a][n][1], SC, -mrun[a]));
        p23.x = exp2f(fmaf(st[a][n][2], SC, -mrun[a]));
        p23.y = exp2f(fmaf(st[a][n][3], SC, -mrun[a]));
        __hip_bfloat162 b01 = __float22bfloat162_rn(p01);
        __hip_bfloat162 b23 = __float22bfloat162_rn(p23);
        uint2 w;
        w.x = *(unsigned*)&b01;
        w.y = *(unsigned*)&b23;
        *(uint2*)(Pb + (a * 16 + lr) * 144 + n * 32 + lk * 8) = w;
      }
    asm volatile("s_waitcnt lgkmcnt(0)" ::: "memory");
    __builtin_amdgcn_sched_barrier(0);

    // O += P V ; lsum += P * ones
#pragma unroll
    for (int kb = 0; kb < 2; ++kb) {
      short8 pf0 = *(const short8*)(Pb + (0 * 16 + lr) * 144 + kb * 64 + lk * 16);
      short8 pf1 = *(const short8*)(Pb + (1 * 16 + lr) * 144 + kb * 64 + lk * 16);
#pragma unroll
      for (int nd = 0; nd < 4; ++nd) {
        o[0][nd] = MFMA_BF16(pf0, vreg[kb][nd], o[0][nd]);
        o[1][nd] = MFMA_BF16(pf1, vreg[kb][nd], o[1][nd]);
      }
      lsum[0] = MFMA_BF16(pf0, vones, lsum[0]);
      lsum[1] = MFMA_BF16(pf1, vones, lsum[1]);
    }
  }

  // ---- flash merge across the 4 waves ----
  if (lk == 0) {
    Lm[wid][0][lr] = mrun[0];
    Lm[wid][1][lr] = mrun[1];
  }
  __syncthreads();

  float sc2[2][4];
#pragma unroll
  for (int a = 0; a < 2; ++a)
#pragma unroll
    for (int r = 0; r < 4; ++r) {
      int row = lk * 4 + r;
      float ms = fmaxf(fmaxf(Lm[0][a][row], Lm[1][a][row]),
                       fmaxf(Lm[2][a][row], Lm[3][a][row]));
      sc2[a][r] = exp2f(Lm[wid][a][row] - ms);  // 0 for waves with no tiles
    }

#pragma unroll
  for (int w = 0; w < 4; ++w) {
    if (wid == w) {
#pragma unroll
      for (int a = 0; a < 2; ++a) {
#pragma unroll
        for (int nd = 0; nd < 4; ++nd) {
          float* dst = &Om[nd * 16 + lr][a * 16 + lk * 4];
          float4 v;
          v.x = o[a][nd][0] * sc2[a][0];
          v.y = o[a][nd][1] * sc2[a][1];
          v.z = o[a][nd][2] * sc2[a][2];
          v.w = o[a][nd][3] * sc2[a][3];
          if (w != 0) {
            float4 cur = *(float4*)dst;
            v.x += cur.x; v.y += cur.y; v.z += cur.z; v.w += cur.w;
          }
          *(float4*)dst = v;
        }
        if (lr == 0) {
#pragma unroll
          for (int r = 0; r < 4; ++r) {
            float lv = lsum[a][r] * sc2[a][r];
            if (w != 0) lv += Lf[a][lk * 4 + r];
            Lf[a][lk * 4 + r] = lv;
          }
        }
      }
    }
    __syncthreads();
  }

  if (wid == 0) {
    const int b = bh >> 4, h2 = bh & 15;
#pragma unroll
    for (int a = 0; a < 2; ++a) {
      float inv[4];
#pragma unroll
      for (int r = 0; r < 4; ++r) inv[r] = 1.0f / Lf[a][lk * 4 + r];
#pragma unroll
      for (int nd = 0; nd < 4; ++nd) {
        float4 v = *(float4*)&Om[nd * 16 + lr][a * 16 + lk * 4];
        float vv[4] = {v.x, v.y, v.z, v.w};
#pragma unroll
        for (int r = 0; r < 4; ++r) {
          int t = q0 + a * 16 + lk * 4 + r;
          ctx[((size_t)b * T_ + t) * E_ + h2 * D_ + nd * 16 + lr] = f2bf(vv[r] * inv[r]);
        }
      }
    }
  }
}

// ---------------- launcher ----------------
extern "C" void kernel_launch(void* const* d_in, const int* in_sizes, int n_in,
                              void* d_out, int out_size, void* d_ws, size_t ws_size,
                              hipStream_t stream) {
  const float* x    = (const float*)d_in[0];
  const float* Wq   = (const float*)d_in[1];
  const float* Wk   = (const float*)d_in[2];
  const float* Wv   = (const float*)d_in[3];
  const float* Wout = (const float*)d_in[4];
  const float* bout = (const float*)d_in[5];
  float* out = (float*)d_out;

  const size_t MT = (size_t)B_ * T_;      // 8192
  const size_t XE = MT * E_;              // 8,388,608
  const size_t WE = (size_t)E_ * E_;      // 1,048,576

  size_t need = (XE * 5 + WE * 4) * sizeof(unsigned short);
  if (ws_size < need) return;

  unsigned short* xb  = (unsigned short*)d_ws;
  unsigned short* wqb = xb + XE;
  unsigned short* wkb = wqb + WE;
  unsigned short* wvb = wkb + WE;
  unsigned short* wob = wvb + WE;
  unsigned short* Qb  = wob + WE;
  unsigned short* Kb  = Qb + XE;
  unsigned short* VTb = Kb + XE;
  unsigned short* ctx = VTb + XE;

  cvt_f32_bf16<<<(int)(XE / 8 / 256), 256, 0, stream>>>(x, xb, (int)(XE / 8));
  cvt_w4<<<2048, 256, 0, stream>>>(Wq, Wk, Wv, Wout, wqb);

  gemm_qkv<<<dim3(MT / 128, 24), 256, 0, stream>>>(xb, wqb, wkb, wvb, Qb, Kb, ctx);  // V -> ctx (temp)

  transpose_v<<<dim3(T_ / 64, B_ * H_), 256, 0, stream>>>(ctx, VTb);

  attn_fused<<<4096, 256, 0, stream>>>(Qb, Kb, VTb, ctx);

  gemm_out<<<dim3(MT / 128, E_ / 128), 256, 0, stream>>>(ctx, wob, out, bout, (int)MT, E_, E_);
}

// Round 9
// 275.055 us; speedup vs baseline: 1.1109x; 1.1109x over previous
//
#include <hip/hip_runtime.h>
#include <hip/hip_bf16.h>
#include <stdint.h>
#include <math.h>

#define B_ 4
#define T_ 2048
#define E_ 1024
#define H_ 16
#define D_ 64

typedef __attribute__((ext_vector_type(8))) short short8;
typedef __attribute__((ext_vector_type(4))) float f32x4;

#define MFMA_BF16(a, b, c) __builtin_amdgcn_mfma_f32_16x16x32_bf16((a), (b), (c), 0, 0, 0)

__device__ __forceinline__ unsigned short f2bf(float f) {
  union { float f; unsigned u; } v; v.f = f;
  unsigned r = v.u + 0x7FFFu + ((v.u >> 16) & 1u);  // RNE
  return (unsigned short)(r >> 16);
}

#define GLOAD_LDS16(g, l)                                                        \
  __builtin_amdgcn_global_load_lds((const __attribute__((address_space(1))) void*)(g), \
                                   (__attribute__((address_space(3))) void*)(l), 16, 0, 0)

// ---------------- fp32 -> bf16 convert (vectorized) ----------------
__global__ __launch_bounds__(256) void cvt_f32_bf16(const float* __restrict__ in,
                                                    unsigned short* __restrict__ out,
                                                    int n8) {
  int i = blockIdx.x * blockDim.x + threadIdx.x;
  if (i >= n8) return;
  const float4* p = (const float4*)(in + (size_t)i * 8);
  float4 a = p[0], b = p[1];
  short8 r;
  r[0] = (short)f2bf(a.x); r[1] = (short)f2bf(a.y);
  r[2] = (short)f2bf(a.z); r[3] = (short)f2bf(a.w);
  r[4] = (short)f2bf(b.x); r[5] = (short)f2bf(b.y);
  r[6] = (short)f2bf(b.z); r[7] = (short)f2bf(b.w);
  *(short8*)(out + (size_t)i * 8) = r;
}

// 4 weight matrices in one launch (dest regions contiguous in ws)
__global__ __launch_bounds__(256) void cvt_w4(const float* __restrict__ w0,
                                              const float* __restrict__ w1,
                                              const float* __restrict__ w2,
                                              const float* __restrict__ w3,
                                              unsigned short* __restrict__ out) {
  int i = blockIdx.x * blockDim.x + threadIdx.x;  // one per 8 elems
  int which = i >> 17;                            // WE/8 = 2^17
  int off = i & 131071;
  const float* src = (which == 0) ? w0 : (which == 1) ? w1 : (which == 2) ? w2 : w3;
  const float4* p = (const float4*)(src + (size_t)off * 8);
  float4 a = p[0], b = p[1];
  short8 r;
  r[0] = (short)f2bf(a.x); r[1] = (short)f2bf(a.y);
  r[2] = (short)f2bf(a.z); r[3] = (short)f2bf(a.w);
  r[4] = (short)f2bf(b.x); r[5] = (short)f2bf(b.y);
  r[6] = (short)f2bf(b.z); r[7] = (short)f2bf(b.w);
  *(short8*)(out + ((size_t)which << 20) + (size_t)off * 8) = r;
}

// ---------------- fused QKV GEMM: C = x * W^T for W in {Wq,Wk,Wv} -------------
__global__ __launch_bounds__(256) void gemm_qkv(const unsigned short* __restrict__ A,
                                                const unsigned short* __restrict__ Wq,
                                                const unsigned short* __restrict__ Wk,
                                                const unsigned short* __restrict__ Wv,
                                                unsigned short* __restrict__ Qo,
                                                unsigned short* __restrict__ Ko,
                                                unsigned short* __restrict__ Vo) {
  __shared__ __align__(16) unsigned short Ab[128 * 64];
  __shared__ __align__(16) unsigned short Bb[128 * 64];
  const int K = E_;
  const int tid = threadIdx.x;
  const int wid = tid >> 6;
  const int lr = tid & 15;
  const int lk = (tid >> 4) & 3;
  const int wr = wid >> 1, wc = wid & 1;
  const int m0 = blockIdx.x * 128;
  const int sel = blockIdx.y >> 3;
  const int n0 = (blockIdx.y & 7) * 128;
  const unsigned short* Bm = (sel == 0) ? Wq : (sel == 1) ? Wk : Wv;
  unsigned short* outp = (sel == 0) ? Qo : (sel == 1) ? Ko : Vo;

  f32x4 acc[4][4] = {};

  for (int k0 = 0; k0 < K; k0 += 64) {
    __syncthreads();
#pragma unroll
    for (int pass = 0; pass < 4; ++pass) {
      int chunk = pass * 256 + tid;
      int row = chunk >> 3, inner = chunk & 7;
      const unsigned short* ga = A + (size_t)(m0 + row) * K + k0 + inner * 8;
      const unsigned short* gb = Bm + (size_t)(n0 + row) * K + k0 + inner * 8;
      unsigned short* la = Ab + (size_t)(pass * 256 + wid * 64) * 8;
      unsigned short* lb = Bb + (size_t)(pass * 256 + wid * 64) * 8;
      GLOAD_LDS16(ga, la);
      GLOAD_LDS16(gb, lb);
    }
    __syncthreads();
#pragma unroll
    for (int kk = 0; kk < 2; ++kk) {
      short8 af[4], bf[4];
#pragma unroll
      for (int mi = 0; mi < 4; ++mi)
        af[mi] = *(const short8*)&Ab[(wr * 64 + mi * 16 + lr) * 64 + kk * 32 + lk * 8];
#pragma unroll
      for (int ni = 0; ni < 4; ++ni)
        bf[ni] = *(const short8*)&Bb[(wc * 64 + ni * 16 + lr) * 64 + kk * 32 + lk * 8];
#pragma unroll
      for (int mi = 0; mi < 4; ++mi)
#pragma unroll
        for (int ni = 0; ni < 4; ++ni)
          acc[mi][ni] = MFMA_BF16(af[mi], bf[ni], acc[mi][ni]);
    }
  }

#pragma unroll
  for (int mi = 0; mi < 4; ++mi)
#pragma unroll
    for (int ni = 0; ni < 4; ++ni)
#pragma unroll
      for (int r = 0; r < 4; ++r) {
        int row = m0 + wr * 64 + mi * 16 + lk * 4 + r;
        int col = n0 + wc * 64 + ni * 16 + lr;
        int b = row >> 11, t = row & (T_ - 1), h = col >> 6, d = col & (D_ - 1);
        outp[(((size_t)(b * H_ + h)) * T_ + t) * D_ + d] = f2bf(acc[mi][ni][r]);
      }
}

// ---------------- out-proj GEMM: fp32 out + bias ----------------
__global__ __launch_bounds__(256) void gemm_out(const unsigned short* __restrict__ A,
                                                const unsigned short* __restrict__ Bm,
                                                float* __restrict__ outp,
                                                const float* __restrict__ bias,
                                                int M, int N, int K) {
  __shared__ __align__(16) unsigned short Ab[128 * 64];
  __shared__ __align__(16) unsigned short Bb[128 * 64];
  const int tid = threadIdx.x;
  const int wid = tid >> 6;
  const int lr = tid & 15;
  const int lk = (tid >> 4) & 3;
  const int wr = wid >> 1, wc = wid & 1;
  const int m0 = blockIdx.x * 128, n0 = blockIdx.y * 128;

  f32x4 acc[4][4] = {};

  for (int k0 = 0; k0 < K; k0 += 64) {
    __syncthreads();
#pragma unroll
    for (int pass = 0; pass < 4; ++pass) {
      int chunk = pass * 256 + tid;
      int row = chunk >> 3, inner = chunk & 7;
      const unsigned short* ga = A + (size_t)(m0 + row) * K + k0 + inner * 8;
      const unsigned short* gb = Bm + (size_t)(n0 + row) * K + k0 + inner * 8;
      unsigned short* la = Ab + (size_t)(pass * 256 + wid * 64) * 8;
      unsigned short* lb = Bb + (size_t)(pass * 256 + wid * 64) * 8;
      GLOAD_LDS16(ga, la);
      GLOAD_LDS16(gb, lb);
    }
    __syncthreads();
#pragma unroll
    for (int kk = 0; kk < 2; ++kk) {
      short8 af[4], bf[4];
#pragma unroll
      for (int mi = 0; mi < 4; ++mi)
        af[mi] = *(const short8*)&Ab[(wr * 64 + mi * 16 + lr) * 64 + kk * 32 + lk * 8];
#pragma unroll
      for (int ni = 0; ni < 4; ++ni)
        bf[ni] = *(const short8*)&Bb[(wc * 64 + ni * 16 + lr) * 64 + kk * 32 + lk * 8];
#pragma unroll
      for (int mi = 0; mi < 4; ++mi)
#pragma unroll
        for (int ni = 0; ni < 4; ++ni)
          acc[mi][ni] = MFMA_BF16(af[mi], bf[ni], acc[mi][ni]);
    }
  }

#pragma unroll
  for (int mi = 0; mi < 4; ++mi)
#pragma unroll
    for (int ni = 0; ni < 4; ++ni)
#pragma unroll
      for (int r = 0; r < 4; ++r) {
        int row = m0 + wr * 64 + mi * 16 + lk * 4 + r;
        int col = n0 + wc * 64 + ni * 16 + lr;
        outp[(size_t)row * N + col] = acc[mi][ni][r] + bias[col];
      }
}

// ---------------- V transpose: [BH][T][D] -> [BH][D][T] ----------------
__global__ __launch_bounds__(256) void transpose_v(const unsigned short* __restrict__ V,
                                                   unsigned short* __restrict__ VT) {
  const int lane = threadIdx.x & 63;
  const int w = threadIdx.x >> 6;
  const int tb = blockIdx.x * 64;
  const int bh = blockIdx.y;
  const unsigned short* Vh = V + (size_t)bh * T_ * D_;
  unsigned short* Vo = VT + (size_t)bh * T_ * D_;
  short8 v0, v1;
#pragma unroll
  for (int j = 0; j < 8; ++j)
    v0[j] = (short)Vh[(size_t)(tb + w * 16 + j) * D_ + lane];
#pragma unroll
  for (int j = 0; j < 8; ++j)
    v1[j] = (short)Vh[(size_t)(tb + w * 16 + 8 + j) * D_ + lane];
  *(short8*)&Vo[(size_t)lane * T_ + tb + w * 16] = v0;
  *(short8*)&Vo[(size_t)lane * T_ + tb + w * 16 + 8] = v1;
}

// ---------------- fused causal flash attention (register-lean) ----------------
// 4096 blocks x 64 thr; one 32-row q-chunk per wave. __launch_bounds__(64,4)
// caps TOTAL regs (arch+acc unified file) at 128 -> 4 waves/SIMD residency.
// Register diet vs round 5: QK split by k-half (4 K-frags live, not 8);
// V loaded per-kb inside PV (after st dies). Latency cost covered by TLP.
__global__ __launch_bounds__(64, 4) void attn_fused(const unsigned short* __restrict__ Q,
                                                    const unsigned short* __restrict__ K,
                                                    const unsigned short* __restrict__ VT,
                                                    unsigned short* __restrict__ ctx) {
  __shared__ __align__(16) unsigned short Pl[32 * 72];  // 32 rows x 144 B
  const int lane = threadIdx.x & 63;
  const int lr = lane & 15;
  const int lk = lane >> 4;

  // XCD swizzle: 8 heads/XCD; heaviest chunks dispatched first.
  const int bid = blockIdx.x;
  const int xcd = bid & 7;
  const int p = bid >> 3;           // 0..511 per XCD
  const int chunk = 63 - (p >> 3);  // heavy first
  const int bh = xcd * 8 + (p & 7);
  const int q0 = chunk * 32;

  const unsigned short* Qh = Q + (size_t)bh * T_ * D_;
  const unsigned short* Kh = K + (size_t)bh * T_ * D_;
  const unsigned short* Vh = VT + (size_t)bh * T_ * D_;  // [D][T]
  char* Pb = (char*)Pl;

  const float SC = 0.125f * 1.44269504089f;  // 1/sqrt(D) * log2(e)

  short8 vones;
#pragma unroll
  for (int j = 0; j < 8; ++j) vones[j] = (short)0x3F80;  // bf16 1.0

  // Q as B-operand: col=q=lr, k=d
  short8 qf[2][2];
#pragma unroll
  for (int a = 0; a < 2; ++a)
#pragma unroll
    for (int kb = 0; kb < 2; ++kb)
      qf[a][kb] = *(const short8*)&Qh[(size_t)(q0 + a * 16 + lr) * D_ + kb * 32 + lk * 8];

  f32x4 o[2][4] = {};
  f32x4 lsum[2] = {};
  float mrun[2] = {-1e30f, -1e30f};

  const int nt = (q0 >> 6) + 1;
  const int ql0 = q0 & 63;  // q-local base within diag tile

  for (int kvt = 0; kvt < nt; ++kvt) {
    const unsigned short* Kt = Kh + (size_t)kvt * 64 * D_;
    const unsigned short* Vtt = Vh + (size_t)kvt * 64;

    // S^T = K Q^T, split by k-half so only 4 K-fragments are live at once.
    f32x4 st[2][4] = {};
    {
      short8 kf[4];
#pragma unroll
      for (int n = 0; n < 4; ++n)
        kf[n] = *(const short8*)&Kt[(size_t)(n * 16 + lr) * D_ + lk * 8];
#pragma unroll
      for (int a = 0; a < 2; ++a)
#pragma unroll
        for (int n = 0; n < 4; ++n)
          st[a][n] = MFMA_BF16(kf[n], qf[a][0], st[a][n]);
    }
    {
      short8 kf[4];
#pragma unroll
      for (int n = 0; n < 4; ++n)
        kf[n] = *(const short8*)&Kt[(size_t)(n * 16 + lr) * D_ + 32 + lk * 8];
#pragma unroll
      for (int a = 0; a < 2; ++a)
#pragma unroll
        for (int n = 0; n < 4; ++n)
          st[a][n] = MFMA_BF16(kf[n], qf[a][1], st[a][n]);
    }

    if (kvt == nt - 1) {  // diagonal tile: mask kv_local > q_local
#pragma unroll
      for (int a = 0; a < 2; ++a)
#pragma unroll
        for (int n = 0; n < 4; ++n)
#pragma unroll
          for (int r = 0; r < 4; ++r)
            if (n * 16 + lk * 4 + r > ql0 + a * 16 + lr) st[a][n][r] = -3e38f;
    }

    // row max (in-lane tree + 2 shuffles)
    float pm[2];
#pragma unroll
    for (int a = 0; a < 2; ++a) {
      float m0 = fmaxf(fmaxf(st[a][0][0], st[a][1][0]), fmaxf(st[a][2][0], st[a][3][0]));
      float m1 = fmaxf(fmaxf(st[a][0][1], st[a][1][1]), fmaxf(st[a][2][1], st[a][3][1]));
      float m2 = fmaxf(fmaxf(st[a][0][2], st[a][1][2]), fmaxf(st[a][2][2], st[a][3][2]));
      float m3 = fmaxf(fmaxf(st[a][0][3], st[a][1][3]), fmaxf(st[a][2][3], st[a][3][3]));
      float mx = fmaxf(fmaxf(m0, m1), fmaxf(m2, m3));
      mx = fmaxf(mx, __shfl_xor(mx, 16));
      mx = fmaxf(mx, __shfl_xor(mx, 32));
      pm[a] = mx * SC;
    }
    float need = fmaxf(pm[0] - mrun[0], pm[1] - mrun[1]);

    if (__any(need > 8.f)) {  // defer-max rescale (rare)
#pragma unroll
      for (int a = 0; a < 2; ++a) {
        float mnew = fmaxf(mrun[a], pm[a]);
        float sc = exp2f(mrun[a] - mnew);
        mrun[a] = mnew;
#pragma unroll
        for (int r = 0; r < 4; ++r) {
          float sco = __shfl(sc, (lane & 48) | (lk * 4 + r));
          lsum[a][r] *= sco;
#pragma unroll
          for (int nd = 0; nd < 4; ++nd) o[a][nd][r] *= sco;
        }
      }
    }

    // P = exp2(S*SC - m), packed bf16x4 -> LDS (8x ds_write_b64, stride 144)
#pragma unroll
    for (int a = 0; a < 2; ++a)
#pragma unroll
      for (int n = 0; n < 4; ++n) {
        float2 p01, p23;
        p01.x = exp2f(fmaf(st[a][n][0], SC, -mrun[a]));
        p01.y = exp2f(fmaf(st[a][n][1], SC, -mrun[a]));
        p23.x = exp2f(fmaf(st[a][n][2], SC, -mrun[a]));
        p23.y = exp2f(fmaf(st[a][n][3], SC, -mrun[a]));
        __hip_bfloat162 b01 = __float22bfloat162_rn(p01);
        __hip_bfloat162 b23 = __float22bfloat162_rn(p23);
        uint2 w;
        w.x = *(unsigned*)&b01;
        w.y = *(unsigned*)&b23;
        *(uint2*)(Pb + (a * 16 + lr) * 144 + n * 32 + lk * 8) = w;
      }
    asm volatile("s_waitcnt lgkmcnt(0)" ::: "memory");
    __builtin_amdgcn_sched_barrier(0);

    // O += P V ; lsum += P * ones  (V loaded per k-half; st dead here)
#pragma unroll
    for (int kb = 0; kb < 2; ++kb) {
      short8 vreg[4];
#pragma unroll
      for (int nd = 0; nd < 4; ++nd)
        vreg[nd] = *(const short8*)&Vtt[(size_t)(nd * 16 + lr) * T_ + kb * 32 + lk * 8];
      short8 pf0 = *(const short8*)(Pb + (0 * 16 + lr) * 144 + kb * 64 + lk * 16);
      short8 pf1 = *(const short8*)(Pb + (1 * 16 + lr) * 144 + kb * 64 + lk * 16);
#pragma unroll
      for (int nd = 0; nd < 4; ++nd) {
        o[0][nd] = MFMA_BF16(pf0, vreg[nd], o[0][nd]);
        o[1][nd] = MFMA_BF16(pf1, vreg[nd], o[1][nd]);
      }
      lsum[0] = MFMA_BF16(pf0, vones, lsum[0]);
      lsum[1] = MFMA_BF16(pf1, vones, lsum[1]);
    }
  }

  const int b = bh >> 4, h2 = bh & 15;
#pragma unroll
  for (int a = 0; a < 2; ++a)
#pragma unroll
    for (int r = 0; r < 4; ++r) {
      float inv = 1.0f / lsum[a][r];
      int t = q0 + a * 16 + lk * 4 + r;
#pragma unroll
      for (int nd = 0; nd < 4; ++nd)
        ctx[((size_t)b * T_ + t) * E_ + h2 * D_ + nd * 16 + lr] = f2bf(o[a][nd][r] * inv);
    }
}

// ---------------- launcher ----------------
extern "C" void kernel_launch(void* const* d_in, const int* in_sizes, int n_in,
                              void* d_out, int out_size, void* d_ws, size_t ws_size,
                              hipStream_t stream) {
  const float* x    = (const float*)d_in[0];
  const float* Wq   = (const float*)d_in[1];
  const float* Wk   = (const float*)d_in[2];
  const float* Wv   = (const float*)d_in[3];
  const float* Wout = (const float*)d_in[4];
  const float* bout = (const float*)d_in[5];
  float* out = (float*)d_out;

  const size_t MT = (size_t)B_ * T_;      // 8192
  const size_t XE = MT * E_;              // 8,388,608
  const size_t WE = (size_t)E_ * E_;      // 1,048,576

  size_t need = (XE * 5 + WE * 4) * sizeof(unsigned short);
  if (ws_size < need) return;

  unsigned short* xb  = (unsigned short*)d_ws;
  unsigned short* wqb = xb + XE;
  unsigned short* wkb = wqb + WE;
  unsigned short* wvb = wkb + WE;
  unsigned short* wob = wvb + WE;
  unsigned short* Qb  = wob + WE;
  unsigned short* Kb  = Qb + XE;
  unsigned short* VTb = Kb + XE;
  unsigned short* ctx = VTb + XE;

  cvt_f32_bf16<<<(int)(XE / 8 / 256), 256, 0, stream>>>(x, xb, (int)(XE / 8));
  cvt_w4<<<2048, 256, 0, stream>>>(Wq, Wk, Wv, Wout, wqb);

  gemm_qkv<<<dim3(MT / 128, 24), 256, 0, stream>>>(xb, wqb, wkb, wvb, Qb, Kb, ctx);  // V -> ctx (temp)

  transpose_v<<<dim3(T_ / 64, B_ * H_), 256, 0, stream>>>(ctx, VTb);

  attn_fused<<<4096, 64, 0, stream>>>(Qb, Kb, VTb, ctx);

  gemm_out<<<dim3(MT / 128, E_ / 128), 256, 0, stream>>>(ctx, wob, out, bout, (int)MT, E_, E_);
}

// Round 10
// 227.160 us; speedup vs baseline: 1.3451x; 1.2108x over previous
//
#include <hip/hip_runtime.h>
#include <hip/hip_bf16.h>
#include <stdint.h>
#include <math.h>

#define B_ 4
#define T_ 2048
#define E_ 1024
#define H_ 16
#define D_ 64

typedef __attribute__((ext_vector_type(8))) short short8;
typedef __attribute__((ext_vector_type(4))) float f32x4;

#define MFMA_BF16(a, b, c) __builtin_amdgcn_mfma_f32_16x16x32_bf16((a), (b), (c), 0, 0, 0)

__device__ __forceinline__ unsigned short f2bf(float f) {
  union { float f; unsigned u; } v; v.f = f;
  unsigned r = v.u + 0x7FFFu + ((v.u >> 16) & 1u);  // RNE
  return (unsigned short)(r >> 16);
}

#define GLOAD_LDS16(g, l)                                                        \
  __builtin_amdgcn_global_load_lds((const __attribute__((address_space(1))) void*)(g), \
                                   (__attribute__((address_space(3))) void*)(l), 16, 0, 0)

// ---------------- fp32 -> bf16 convert (vectorized) ----------------
__global__ __launch_bounds__(256) void cvt_f32_bf16(const float* __restrict__ in,
                                                    unsigned short* __restrict__ out,
                                                    int n8) {
  int i = blockIdx.x * blockDim.x + threadIdx.x;
  if (i >= n8) return;
  const float4* p = (const float4*)(in + (size_t)i * 8);
  float4 a = p[0], b = p[1];
  short8 r;
  r[0] = (short)f2bf(a.x); r[1] = (short)f2bf(a.y);
  r[2] = (short)f2bf(a.z); r[3] = (short)f2bf(a.w);
  r[4] = (short)f2bf(b.x); r[5] = (short)f2bf(b.y);
  r[6] = (short)f2bf(b.z); r[7] = (short)f2bf(b.w);
  *(short8*)(out + (size_t)i * 8) = r;
}

// 4 weight matrices in one launch (dest regions contiguous in ws)
__global__ __launch_bounds__(256) void cvt_w4(const float* __restrict__ w0,
                                              const float* __restrict__ w1,
                                              const float* __restrict__ w2,
                                              const float* __restrict__ w3,
                                              unsigned short* __restrict__ out) {
  int i = blockIdx.x * blockDim.x + threadIdx.x;  // one per 8 elems
  int which = i >> 17;                            // WE/8 = 2^17
  int off = i & 131071;
  const float* src = (which == 0) ? w0 : (which == 1) ? w1 : (which == 2) ? w2 : w3;
  const float4* p = (const float4*)(src + (size_t)off * 8);
  float4 a = p[0], b = p[1];
  short8 r;
  r[0] = (short)f2bf(a.x); r[1] = (short)f2bf(a.y);
  r[2] = (short)f2bf(a.z); r[3] = (short)f2bf(a.w);
  r[4] = (short)f2bf(b.x); r[5] = (short)f2bf(b.y);
  r[6] = (short)f2bf(b.z); r[7] = (short)f2bf(b.w);
  *(short8*)(out + ((size_t)which << 20) + (size_t)off * 8) = r;
}

// ---------------- fused QKV GEMM: C = x * W^T for W in {Wq,Wk,Wv} -------------
__global__ __launch_bounds__(256) void gemm_qkv(const unsigned short* __restrict__ A,
                                                const unsigned short* __restrict__ Wq,
                                                const unsigned short* __restrict__ Wk,
                                                const unsigned short* __restrict__ Wv,
                                                unsigned short* __restrict__ Qo,
                                                unsigned short* __restrict__ Ko,
                                                unsigned short* __restrict__ Vo) {
  __shared__ __align__(16) unsigned short Ab[128 * 64];
  __shared__ __align__(16) unsigned short Bb[128 * 64];
  const int K = E_;
  const int tid = threadIdx.x;
  const int wid = tid >> 6;
  const int lr = tid & 15;
  const int lk = (tid >> 4) & 3;
  const int wr = wid >> 1, wc = wid & 1;
  const int m0 = blockIdx.x * 128;
  const int sel = blockIdx.y >> 3;
  const int n0 = (blockIdx.y & 7) * 128;
  const unsigned short* Bm = (sel == 0) ? Wq : (sel == 1) ? Wk : Wv;
  unsigned short* outp = (sel == 0) ? Qo : (sel == 1) ? Ko : Vo;

  f32x4 acc[4][4] = {};

  for (int k0 = 0; k0 < K; k0 += 64) {
    __syncthreads();
#pragma unroll
    for (int pass = 0; pass < 4; ++pass) {
      int chunk = pass * 256 + tid;
      int row = chunk >> 3, inner = chunk & 7;
      const unsigned short* ga = A + (size_t)(m0 + row) * K + k0 + inner * 8;
      const unsigned short* gb = Bm + (size_t)(n0 + row) * K + k0 + inner * 8;
      unsigned short* la = Ab + (size_t)(pass * 256 + wid * 64) * 8;
      unsigned short* lb = Bb + (size_t)(pass * 256 + wid * 64) * 8;
      GLOAD_LDS16(ga, la);
      GLOAD_LDS16(gb, lb);
    }
    __syncthreads();
#pragma unroll
    for (int kk = 0; kk < 2; ++kk) {
      short8 af[4], bf[4];
#pragma unroll
      for (int mi = 0; mi < 4; ++mi)
        af[mi] = *(const short8*)&Ab[(wr * 64 + mi * 16 + lr) * 64 + kk * 32 + lk * 8];
#pragma unroll
      for (int ni = 0; ni < 4; ++ni)
        bf[ni] = *(const short8*)&Bb[(wc * 64 + ni * 16 + lr) * 64 + kk * 32 + lk * 8];
#pragma unroll
      for (int mi = 0; mi < 4; ++mi)
#pragma unroll
        for (int ni = 0; ni < 4; ++ni)
          acc[mi][ni] = MFMA_BF16(af[mi], bf[ni], acc[mi][ni]);
    }
  }

#pragma unroll
  for (int mi = 0; mi < 4; ++mi)
#pragma unroll
    for (int ni = 0; ni < 4; ++ni)
#pragma unroll
      for (int r = 0; r < 4; ++r) {
        int row = m0 + wr * 64 + mi * 16 + lk * 4 + r;
        int col = n0 + wc * 64 + ni * 16 + lr;
        int b = row >> 11, t = row & (T_ - 1), h = col >> 6, d = col & (D_ - 1);
        outp[(((size_t)(b * H_ + h)) * T_ + t) * D_ + d] = f2bf(acc[mi][ni][r]);
      }
}

// ---------------- out-proj GEMM: fp32 out + bias ----------------
__global__ __launch_bounds__(256) void gemm_out(const unsigned short* __restrict__ A,
                                                const unsigned short* __restrict__ Bm,
                                                float* __restrict__ outp,
                                                const float* __restrict__ bias,
                                                int M, int N, int K) {
  __shared__ __align__(16) unsigned short Ab[128 * 64];
  __shared__ __align__(16) unsigned short Bb[128 * 64];
  const int tid = threadIdx.x;
  const int wid = tid >> 6;
  const int lr = tid & 15;
  const int lk = (tid >> 4) & 3;
  const int wr = wid >> 1, wc = wid & 1;
  const int m0 = blockIdx.x * 128, n0 = blockIdx.y * 128;

  f32x4 acc[4][4] = {};

  for (int k0 = 0; k0 < K; k0 += 64) {
    __syncthreads();
#pragma unroll
    for (int pass = 0; pass < 4; ++pass) {
      int chunk = pass * 256 + tid;
      int row = chunk >> 3, inner = chunk & 7;
      const unsigned short* ga = A + (size_t)(m0 + row) * K + k0 + inner * 8;
      const unsigned short* gb = Bm + (size_t)(n0 + row) * K + k0 + inner * 8;
      unsigned short* la = Ab + (size_t)(pass * 256 + wid * 64) * 8;
      unsigned short* lb = Bb + (size_t)(pass * 256 + wid * 64) * 8;
      GLOAD_LDS16(ga, la);
      GLOAD_LDS16(gb, lb);
    }
    __syncthreads();
#pragma unroll
    for (int kk = 0; kk < 2; ++kk) {
      short8 af[4], bf[4];
#pragma unroll
      for (int mi = 0; mi < 4; ++mi)
        af[mi] = *(const short8*)&Ab[(wr * 64 + mi * 16 + lr) * 64 + kk * 32 + lk * 8];
#pragma unroll
      for (int ni = 0; ni < 4; ++ni)
        bf[ni] = *(const short8*)&Bb[(wc * 64 + ni * 16 + lr) * 64 + kk * 32 + lk * 8];
#pragma unroll
      for (int mi = 0; mi < 4; ++mi)
#pragma unroll
        for (int ni = 0; ni < 4; ++ni)
          acc[mi][ni] = MFMA_BF16(af[mi], bf[ni], acc[mi][ni]);
    }
  }

#pragma unroll
  for (int mi = 0; mi < 4; ++mi)
#pragma unroll
    for (int ni = 0; ni < 4; ++ni)
#pragma unroll
      for (int r = 0; r < 4; ++r) {
        int row = m0 + wr * 64 + mi * 16 + lk * 4 + r;
        int col = n0 + wc * 64 + ni * 16 + lr;
        outp[(size_t)row * N + col] = acc[mi][ni][r] + bias[col];
      }
}

// ---------------- V transpose: [BH][T][D] -> [BH][D][T] ----------------
__global__ __launch_bounds__(256) void transpose_v(const unsigned short* __restrict__ V,
                                                   unsigned short* __restrict__ VT) {
  const int lane = threadIdx.x & 63;
  const int w = threadIdx.x >> 6;
  const int tb = blockIdx.x * 64;
  const int bh = blockIdx.y;
  const unsigned short* Vh = V + (size_t)bh * T_ * D_;
  unsigned short* Vo = VT + (size_t)bh * T_ * D_;
  short8 v0, v1;
#pragma unroll
  for (int j = 0; j < 8; ++j)
    v0[j] = (short)Vh[(size_t)(tb + w * 16 + j) * D_ + lane];
#pragma unroll
  for (int j = 0; j < 8; ++j)
    v1[j] = (short)Vh[(size_t)(tb + w * 16 + 8 + j) * D_ + lane];
  *(short8*)&Vo[(size_t)lane * T_ + tb + w * 16] = v0;
  *(short8*)&Vo[(size_t)lane * T_ + tb + w * 16 + 8] = v1;
}

// ---------------- fused causal flash attention (2 q-chunks share K/V) --------
// 2048 blocks x 64 thr; wave owns 64 q-rows [64c, 64c+64) as chunks A/B.
// Both chunks have the SAME trip count nt=c+1, so each tile's K,V fragment
// loads (16 b128) feed 72 MFMAs (2x the r5 intensity); wave-tiles and L2
// traffic halve. P for both chunks packs into one 64x144B LDS buffer.
__global__ __launch_bounds__(64) void attn_fused(const unsigned short* __restrict__ Q,
                                                 const unsigned short* __restrict__ K,
                                                 const unsigned short* __restrict__ VT,
                                                 unsigned short* __restrict__ ctx) {
  __shared__ __align__(16) unsigned short Pl[64 * 72];  // 64 rows x 144 B
  const int lane = threadIdx.x & 63;
  const int lr = lane & 15;
  const int lk = lane >> 4;

  // XCD swizzle: 8 heads/XCD; heaviest pair-chunks dispatched first.
  const int bid = blockIdx.x;
  const int xcd = bid & 7;
  const int p = bid >> 3;       // 0..255 per XCD
  const int bh = xcd * 8 + (p & 7);
  const int c = 31 - (p >> 3);  // heavy first, 0..31
  const int q0 = c * 64;        // chunk A rows q0.., chunk B rows q0+32..

  const unsigned short* Qh = Q + (size_t)bh * T_ * D_;
  const unsigned short* Kh = K + (size_t)bh * T_ * D_;
  const unsigned short* Vh = VT + (size_t)bh * T_ * D_;  // [D][T]
  char* Pb = (char*)Pl;

  const float SC = 0.125f * 1.44269504089f;  // 1/sqrt(D) * log2(e)

  short8 vones;
#pragma unroll
  for (int j = 0; j < 8; ++j) vones[j] = (short)0x3F80;  // bf16 1.0

  // Q as B-operand: col=q=lr, k=d
  short8 qfA[2][2], qfB[2][2];
#pragma unroll
  for (int a = 0; a < 2; ++a)
#pragma unroll
    for (int kb = 0; kb < 2; ++kb) {
      qfA[a][kb] = *(const short8*)&Qh[(size_t)(q0 + a * 16 + lr) * D_ + kb * 32 + lk * 8];
      qfB[a][kb] = *(const short8*)&Qh[(size_t)(q0 + 32 + a * 16 + lr) * D_ + kb * 32 + lk * 8];
    }

  f32x4 oA[2][4] = {}, oB[2][4] = {};
  f32x4 lsumA[2] = {}, lsumB[2] = {};
  float mrunA[2] = {-1e30f, -1e30f}, mrunB[2] = {-1e30f, -1e30f};

  const int nt = c + 1;

  for (int kvt = 0; kvt < nt; ++kvt) {
    const unsigned short* Kt = Kh + (size_t)kvt * 64 * D_;
    const unsigned short* Vtt = Vh + (size_t)kvt * 64;
    const bool diag = (kvt == nt - 1);

    // K fragments, then V fragments (V stays in flight through softmax)
    short8 kf[2][4];
#pragma unroll
    for (int kb = 0; kb < 2; ++kb)
#pragma unroll
      for (int n = 0; n < 4; ++n)
        kf[kb][n] = *(const short8*)&Kt[(size_t)(n * 16 + lr) * D_ + kb * 32 + lk * 8];
    short8 vreg[2][4];
#pragma unroll
    for (int kb = 0; kb < 2; ++kb)
#pragma unroll
      for (int nd = 0; nd < 4; ++nd)
        vreg[kb][nd] = *(const short8*)&Vtt[(size_t)(nd * 16 + lr) * T_ + kb * 32 + lk * 8];

    // S^T for both chunks (kf reused in-register)
    f32x4 stA[2][4] = {}, stB[2][4] = {};
#pragma unroll
    for (int kb = 0; kb < 2; ++kb)
#pragma unroll
      for (int a = 0; a < 2; ++a)
#pragma unroll
        for (int n = 0; n < 4; ++n) {
          stA[a][n] = MFMA_BF16(kf[kb][n], qfA[a][kb], stA[a][n]);
          stB[a][n] = MFMA_BF16(kf[kb][n], qfB[a][kb], stB[a][n]);
        }

    // softmax + pack (chunk X at LDS row base rb)
    auto smpack = [&](f32x4(&st)[2][4], float(&mrun)[2], f32x4(&lsum)[2],
                      f32x4(&o)[2][4], int qlbase, int rb) {
      if (diag) {
#pragma unroll
        for (int a = 0; a < 2; ++a)
#pragma unroll
          for (int n = 0; n < 4; ++n)
#pragma unroll
            for (int r = 0; r < 4; ++r)
              if (n * 16 + lk * 4 + r > qlbase + a * 16 + lr) st[a][n][r] = -3e38f;
      }
      float pm[2];
#pragma unroll
      for (int a = 0; a < 2; ++a) {
        float m0 = fmaxf(fmaxf(st[a][0][0], st[a][1][0]), fmaxf(st[a][2][0], st[a][3][0]));
        float m1 = fmaxf(fmaxf(st[a][0][1], st[a][1][1]), fmaxf(st[a][2][1], st[a][3][1]));
        float m2 = fmaxf(fmaxf(st[a][0][2], st[a][1][2]), fmaxf(st[a][2][2], st[a][3][2]));
        float m3 = fmaxf(fmaxf(st[a][0][3], st[a][1][3]), fmaxf(st[a][2][3], st[a][3][3]));
        float mx = fmaxf(fmaxf(m0, m1), fmaxf(m2, m3));
        mx = fmaxf(mx, __shfl_xor(mx, 16));
        mx = fmaxf(mx, __shfl_xor(mx, 32));
        pm[a] = mx * SC;
      }
      if (__any(fmaxf(pm[0] - mrun[0], pm[1] - mrun[1]) > 8.f)) {
#pragma unroll
        for (int a = 0; a < 2; ++a) {
          float mnew = fmaxf(mrun[a], pm[a]);
          float sc = exp2f(mrun[a] - mnew);
          mrun[a] = mnew;
#pragma unroll
          for (int r = 0; r < 4; ++r) {
            float sco = __shfl(sc, (lane & 48) | (lk * 4 + r));
            lsum[a][r] *= sco;
#pragma unroll
            for (int nd = 0; nd < 4; ++nd) o[a][nd][r] *= sco;
          }
        }
      }
#pragma unroll
      for (int a = 0; a < 2; ++a)
#pragma unroll
        for (int n = 0; n < 4; ++n) {
          float2 p01, p23;
          p01.x = exp2f(fmaf(st[a][n][0], SC, -mrun[a]));
          p01.y = exp2f(fmaf(st[a][n][1], SC, -mrun[a]));
          p23.x = exp2f(fmaf(st[a][n][2], SC, -mrun[a]));
          p23.y = exp2f(fmaf(st[a][n][3], SC, -mrun[a]));
          __hip_bfloat162 b01 = __float22bfloat162_rn(p01);
          __hip_bfloat162 b23 = __float22bfloat162_rn(p23);
          uint2 w;
          w.x = *(unsigned*)&b01;
          w.y = *(unsigned*)&b23;
          *(uint2*)(Pb + (rb + a * 16 + lr) * 144 + n * 32 + lk * 8) = w;
        }
    };

    smpack(stA, mrunA, lsumA, oA, 0, 0);
    smpack(stB, mrunB, lsumB, oB, 32, 32);

    asm volatile("s_waitcnt lgkmcnt(0)" ::: "memory");
    __builtin_amdgcn_sched_barrier(0);

    // O += P V ; lsum += P * ones  (vreg reused for both chunks)
#pragma unroll
    for (int kb = 0; kb < 2; ++kb) {
      short8 pfA0 = *(const short8*)(Pb + (0 + lr) * 144 + kb * 64 + lk * 16);
      short8 pfA1 = *(const short8*)(Pb + (16 + lr) * 144 + kb * 64 + lk * 16);
      short8 pfB0 = *(const short8*)(Pb + (32 + lr) * 144 + kb * 64 + lk * 16);
      short8 pfB1 = *(const short8*)(Pb + (48 + lr) * 144 + kb * 64 + lk * 16);
#pragma unroll
      for (int nd = 0; nd < 4; ++nd) {
        oA[0][nd] = MFMA_BF16(pfA0, vreg[kb][nd], oA[0][nd]);
        oA[1][nd] = MFMA_BF16(pfA1, vreg[kb][nd], oA[1][nd]);
        oB[0][nd] = MFMA_BF16(pfB0, vreg[kb][nd], oB[0][nd]);
        oB[1][nd] = MFMA_BF16(pfB1, vreg[kb][nd], oB[1][nd]);
      }
      lsumA[0] = MFMA_BF16(pfA0, vones, lsumA[0]);
      lsumA[1] = MFMA_BF16(pfA1, vones, lsumA[1]);
      lsumB[0] = MFMA_BF16(pfB0, vones, lsumB[0]);
      lsumB[1] = MFMA_BF16(pfB1, vones, lsumB[1]);
    }
  }

  const int b = bh >> 4, h2 = bh & 15;
#pragma unroll
  for (int a = 0; a < 2; ++a)
#pragma unroll
    for (int r = 0; r < 4; ++r) {
      float invA = 1.0f / lsumA[a][r];
      float invB = 1.0f / lsumB[a][r];
      int tA = q0 + a * 16 + lk * 4 + r;
      int tB = tA + 32;
#pragma unroll
      for (int nd = 0; nd < 4; ++nd) {
        ctx[((size_t)b * T_ + tA) * E_ + h2 * D_ + nd * 16 + lr] = f2bf(oA[a][nd][r] * invA);
        ctx[((size_t)b * T_ + tB) * E_ + h2 * D_ + nd * 16 + lr] = f2bf(oB[a][nd][r] * invB);
      }
    }
}

// ---------------- launcher ----------------
extern "C" void kernel_launch(void* const* d_in, const int* in_sizes, int n_in,
                              void* d_out, int out_size, void* d_ws, size_t ws_size,
                              hipStream_t stream) {
  const float* x    = (const float*)d_in[0];
  const float* Wq   = (const float*)d_in[1];
  const float* Wk   = (const float*)d_in[2];
  const float* Wv   = (const float*)d_in[3];
  const float* Wout = (const float*)d_in[4];
  const float* bout = (const float*)d_in[5];
  float* out = (float*)d_out;

  const size_t MT = (size_t)B_ * T_;      // 8192
  const size_t XE = MT * E_;              // 8,388,608
  const size_t WE = (size_t)E_ * E_;      // 1,048,576

  size_t need = (XE * 5 + WE * 4) * sizeof(unsigned short);
  if (ws_size < need) return;

  unsigned short* xb  = (unsigned short*)d_ws;
  unsigned short* wqb = xb + XE;
  unsigned short* wkb = wqb + WE;
  unsigned short* wvb = wkb + WE;
  unsigned short* wob = wvb + WE;
  unsigned short* Qb  = wob + WE;
  unsigned short* Kb  = Qb + XE;
  unsigned short* VTb = Kb + XE;
  unsigned short* ctx = VTb + XE;

  cvt_f32_bf16<<<(int)(XE / 8 / 256), 256, 0, stream>>>(x, xb, (int)(XE / 8));
  cvt_w4<<<2048, 256, 0, stream>>>(Wq, Wk, Wv, Wout, wqb);

  gemm_qkv<<<dim3(MT / 128, 24), 256, 0, stream>>>(xb, wqb, wkb, wvb, Qb, Kb, ctx);  // V -> ctx (temp)

  transpose_v<<<dim3(T_ / 64, B_ * H_), 256, 0, stream>>>(ctx, VTb);

  attn_fused<<<2048, 64, 0, stream>>>(Qb, Kb, VTb, ctx);

  gemm_out<<<dim3(MT / 128, E_ / 128), 256, 0, stream>>>(ctx, wob, out, bout, (int)MT, E_, E_);
}

// Round 11
// 205.064 us; speedup vs baseline: 1.4901x; 1.1078x over previous
//
#include <hip/hip_runtime.h>
#include <hip/hip_bf16.h>
#include <stdint.h>
#include <math.h>

#define B_ 4
#define T_ 2048
#define E_ 1024
#define H_ 16
#define D_ 64

typedef __attribute__((ext_vector_type(8))) short short8;
typedef __attribute__((ext_vector_type(4))) short short4v;
typedef __attribute__((ext_vector_type(4))) float f32x4;

#define MFMA_BF16(a, b, c) __builtin_amdgcn_mfma_f32_16x16x32_bf16((a), (b), (c), 0, 0, 0)

__device__ __forceinline__ unsigned short f2bf(float f) {
  union { float f; unsigned u; } v; v.f = f;
  unsigned r = v.u + 0x7FFFu + ((v.u >> 16) & 1u);  // RNE
  return (unsigned short)(r >> 16);
}

#define GLOAD_LDS16(g, l)                                                        \
  __builtin_amdgcn_global_load_lds((const __attribute__((address_space(1))) void*)(g), \
                                   (__attribute__((address_space(3))) void*)(l), 16, 0, 0)

// ---------------- fp32 -> bf16 convert (vectorized) ----------------
__global__ __launch_bounds__(256) void cvt_f32_bf16(const float* __restrict__ in,
                                                    unsigned short* __restrict__ out,
                                                    int n8) {
  int i = blockIdx.x * blockDim.x + threadIdx.x;
  if (i >= n8) return;
  const float4* p = (const float4*)(in + (size_t)i * 8);
  float4 a = p[0], b = p[1];
  short8 r;
  r[0] = (short)f2bf(a.x); r[1] = (short)f2bf(a.y);
  r[2] = (short)f2bf(a.z); r[3] = (short)f2bf(a.w);
  r[4] = (short)f2bf(b.x); r[5] = (short)f2bf(b.y);
  r[6] = (short)f2bf(b.z); r[7] = (short)f2bf(b.w);
  *(short8*)(out + (size_t)i * 8) = r;
}

// 4 weight matrices in one launch (dest regions contiguous in ws)
__global__ __launch_bounds__(256) void cvt_w4(const float* __restrict__ w0,
                                              const float* __restrict__ w1,
                                              const float* __restrict__ w2,
                                              const float* __restrict__ w3,
                                              unsigned short* __restrict__ out) {
  int i = blockIdx.x * blockDim.x + threadIdx.x;  // one per 8 elems
  int which = i >> 17;                            // WE/8 = 2^17
  int off = i & 131071;
  const float* src = (which == 0) ? w0 : (which == 1) ? w1 : (which == 2) ? w2 : w3;
  const float4* p = (const float4*)(src + (size_t)off * 8);
  float4 a = p[0], b = p[1];
  short8 r;
  r[0] = (short)f2bf(a.x); r[1] = (short)f2bf(a.y);
  r[2] = (short)f2bf(a.z); r[3] = (short)f2bf(a.w);
  r[4] = (short)f2bf(b.x); r[5] = (short)f2bf(b.y);
  r[6] = (short)f2bf(b.z); r[7] = (short)f2bf(b.w);
  *(short8*)(out + ((size_t)which << 20) + (size_t)off * 8) = r;
}

// ---------------- fused QKV GEMM: C = x * W^T for W in {Wq,Wk,Wv} -------------
// sel 0/1 (Q,K): bf16 [B*H][T][D]. sel 2 (V): bf16 TRANSPOSED [B*H][D][T] via
// packed 8B stores (4 consecutive t at fixed d) — deletes the transpose pass.
__global__ __launch_bounds__(256) void gemm_qkv(const unsigned short* __restrict__ A,
                                                const unsigned short* __restrict__ Wq,
                                                const unsigned short* __restrict__ Wk,
                                                const unsigned short* __restrict__ Wv,
                                                unsigned short* __restrict__ Qo,
                                                unsigned short* __restrict__ Ko,
                                                unsigned short* __restrict__ Vo) {
  __shared__ __align__(16) unsigned short Ab[128 * 64];
  __shared__ __align__(16) unsigned short Bb[128 * 64];
  const int K = E_;
  const int tid = threadIdx.x;
  const int wid = tid >> 6;
  const int lr = tid & 15;
  const int lk = (tid >> 4) & 3;
  const int wr = wid >> 1, wc = wid & 1;
  const int m0 = blockIdx.x * 128;
  const int sel = blockIdx.y >> 3;
  const int n0 = (blockIdx.y & 7) * 128;
  const unsigned short* Bm = (sel == 0) ? Wq : (sel == 1) ? Wk : Wv;
  unsigned short* outp = (sel == 0) ? Qo : (sel == 1) ? Ko : Vo;

  f32x4 acc[4][4] = {};

  for (int k0 = 0; k0 < K; k0 += 64) {
    __syncthreads();
#pragma unroll
    for (int pass = 0; pass < 4; ++pass) {
      int chunk = pass * 256 + tid;
      int row = chunk >> 3, inner = chunk & 7;
      const unsigned short* ga = A + (size_t)(m0 + row) * K + k0 + inner * 8;
      const unsigned short* gb = Bm + (size_t)(n0 + row) * K + k0 + inner * 8;
      unsigned short* la = Ab + (size_t)(pass * 256 + wid * 64) * 8;
      unsigned short* lb = Bb + (size_t)(pass * 256 + wid * 64) * 8;
      GLOAD_LDS16(ga, la);
      GLOAD_LDS16(gb, lb);
    }
    __syncthreads();
#pragma unroll
    for (int kk = 0; kk < 2; ++kk) {
      short8 af[4], bf[4];
#pragma unroll
      for (int mi = 0; mi < 4; ++mi)
        af[mi] = *(const short8*)&Ab[(wr * 64 + mi * 16 + lr) * 64 + kk * 32 + lk * 8];
#pragma unroll
      for (int ni = 0; ni < 4; ++ni)
        bf[ni] = *(const short8*)&Bb[(wc * 64 + ni * 16 + lr) * 64 + kk * 32 + lk * 8];
#pragma unroll
      for (int mi = 0; mi < 4; ++mi)
#pragma unroll
        for (int ni = 0; ni < 4; ++ni)
          acc[mi][ni] = MFMA_BF16(af[mi], bf[ni], acc[mi][ni]);
    }
  }

#pragma unroll
  for (int mi = 0; mi < 4; ++mi)
#pragma unroll
    for (int ni = 0; ni < 4; ++ni) {
      int row0 = m0 + wr * 64 + mi * 16 + lk * 4;
      int col = n0 + wc * 64 + ni * 16 + lr;
      int b = row0 >> 11, t0 = row0 & (T_ - 1), h = col >> 6, d = col & (D_ - 1);
      if (sel == 2) {
        short4v vv;
#pragma unroll
        for (int r = 0; r < 4; ++r) vv[r] = (short)f2bf(acc[mi][ni][r]);
        *(short4v*)&outp[(((size_t)(b * H_ + h)) * D_ + d) * T_ + t0] = vv;  // [BH][D][T]
      } else {
#pragma unroll
        for (int r = 0; r < 4; ++r)
          outp[(((size_t)(b * H_ + h)) * T_ + t0 + r) * D_ + d] = f2bf(acc[mi][ni][r]);
      }
    }
}

// ---------------- out-proj GEMM: fp32 out + bias ----------------
__global__ __launch_bounds__(256) void gemm_out(const unsigned short* __restrict__ A,
                                                const unsigned short* __restrict__ Bm,
                                                float* __restrict__ outp,
                                                const float* __restrict__ bias,
                                                int M, int N, int K) {
  __shared__ __align__(16) unsigned short Ab[128 * 64];
  __shared__ __align__(16) unsigned short Bb[128 * 64];
  const int tid = threadIdx.x;
  const int wid = tid >> 6;
  const int lr = tid & 15;
  const int lk = (tid >> 4) & 3;
  const int wr = wid >> 1, wc = wid & 1;
  const int m0 = blockIdx.x * 128, n0 = blockIdx.y * 128;

  f32x4 acc[4][4] = {};

  for (int k0 = 0; k0 < K; k0 += 64) {
    __syncthreads();
#pragma unroll
    for (int pass = 0; pass < 4; ++pass) {
      int chunk = pass * 256 + tid;
      int row = chunk >> 3, inner = chunk & 7;
      const unsigned short* ga = A + (size_t)(m0 + row) * K + k0 + inner * 8;
      const unsigned short* gb = Bm + (size_t)(n0 + row) * K + k0 + inner * 8;
      unsigned short* la = Ab + (size_t)(pass * 256 + wid * 64) * 8;
      unsigned short* lb = Bb + (size_t)(pass * 256 + wid * 64) * 8;
      GLOAD_LDS16(ga, la);
      GLOAD_LDS16(gb, lb);
    }
    __syncthreads();
#pragma unroll
    for (int kk = 0; kk < 2; ++kk) {
      short8 af[4], bf[4];
#pragma unroll
      for (int mi = 0; mi < 4; ++mi)
        af[mi] = *(const short8*)&Ab[(wr * 64 + mi * 16 + lr) * 64 + kk * 32 + lk * 8];
#pragma unroll
      for (int ni = 0; ni < 4; ++ni)
        bf[ni] = *(const short8*)&Bb[(wc * 64 + ni * 16 + lr) * 64 + kk * 32 + lk * 8];
#pragma unroll
      for (int mi = 0; mi < 4; ++mi)
#pragma unroll
        for (int ni = 0; ni < 4; ++ni)
          acc[mi][ni] = MFMA_BF16(af[mi], bf[ni], acc[mi][ni]);
    }
  }

#pragma unroll
  for (int mi = 0; mi < 4; ++mi)
#pragma unroll
    for (int ni = 0; ni < 4; ++ni)
#pragma unroll
      for (int r = 0; r < 4; ++r) {
        int row = m0 + wr * 64 + mi * 16 + lk * 4 + r;
        int col = n0 + wc * 64 + ni * 16 + lr;
        outp[(size_t)row * N + col] = acc[mi][ni][r] + bias[col];
      }
}

// ---------------- fused causal flash attention (pipelined, lagged PV) --------
// 2048 blocks x 64 thr; wave owns 64 q-rows (chunks A,B) sharing K/V (r10).
// Software pipeline: iter i = {issue K(i+1),V(i) loads; QK(i); rowmax(i);
// PV(i-1) from the OTHER P buffer (packed a full tile ago -> ds latency
// covered); rescale (after PV absorbed old-scale contribution); pack(i)}.
// Double-buffered P, double-buffered K/V regs, no fences (compiler waits).
__global__ __launch_bounds__(64) void attn_fused(const unsigned short* __restrict__ Q,
                                                 const unsigned short* __restrict__ K,
                                                 const unsigned short* __restrict__ VT,
                                                 unsigned short* __restrict__ ctx) {
  __shared__ __align__(16) unsigned short Pl[2][64 * 72];  // 2 bufs x 64 rows x 144B
  const int lane = threadIdx.x & 63;
  const int lr = lane & 15;
  const int lk = lane >> 4;

  // XCD swizzle: 8 heads/XCD; heaviest pair-chunks dispatched first.
  const int bid = blockIdx.x;
  const int xcd = bid & 7;
  const int p = bid >> 3;       // 0..255 per XCD
  const int bh = xcd * 8 + (p & 7);
  const int c = 31 - (p >> 3);  // heavy first, 0..31
  const int q0 = c * 64;

  const unsigned short* Qh = Q + (size_t)bh * T_ * D_;
  const unsigned short* Kh = K + (size_t)bh * T_ * D_;
  const unsigned short* Vh = VT + (size_t)bh * T_ * D_;  // [D][T]
  char* bufA = (char*)&Pl[0][0];
  char* bufB = (char*)&Pl[1][0];

  const float SC = 0.125f * 1.44269504089f;  // 1/sqrt(D) * log2(e)

  short8 vones;
#pragma unroll
  for (int j = 0; j < 8; ++j) vones[j] = (short)0x3F80;  // bf16 1.0

  // Q as B-operand: col=q=lr, k=d
  short8 qfA[2][2], qfB[2][2];
#pragma unroll
  for (int a = 0; a < 2; ++a)
#pragma unroll
    for (int kb = 0; kb < 2; ++kb) {
      qfA[a][kb] = *(const short8*)&Qh[(size_t)(q0 + a * 16 + lr) * D_ + kb * 32 + lk * 8];
      qfB[a][kb] = *(const short8*)&Qh[(size_t)(q0 + 32 + a * 16 + lr) * D_ + kb * 32 + lk * 8];
    }

  f32x4 oA[2][4] = {}, oB[2][4] = {};
  f32x4 lsA[2] = {}, lsB[2] = {};
  float mA[2] = {-1e30f, -1e30f}, mB[2] = {-1e30f, -1e30f};

  const int nt = c + 1;

  auto loadK = [&](short8(&kf)[2][4], int t) {
    const unsigned short* Kt = Kh + (size_t)t * 64 * D_;
#pragma unroll
    for (int kb = 0; kb < 2; ++kb)
#pragma unroll
      for (int n = 0; n < 4; ++n)
        kf[kb][n] = *(const short8*)&Kt[(size_t)(n * 16 + lr) * D_ + kb * 32 + lk * 8];
  };
  auto loadV = [&](short8(&v)[2][4], int t) {
    const unsigned short* Vtt = Vh + (size_t)t * 64;
#pragma unroll
    for (int kb = 0; kb < 2; ++kb)
#pragma unroll
      for (int nd = 0; nd < 4; ++nd)
        v[kb][nd] = *(const short8*)&Vtt[(size_t)(nd * 16 + lr) * T_ + kb * 32 + lk * 8];
  };
  auto rowmax = [&](f32x4(&st)[2][4], float(&pm)[2]) {
#pragma unroll
    for (int a = 0; a < 2; ++a) {
      float m0 = fmaxf(fmaxf(st[a][0][0], st[a][1][0]), fmaxf(st[a][2][0], st[a][3][0]));
      float m1 = fmaxf(fmaxf(st[a][0][1], st[a][1][1]), fmaxf(st[a][2][1], st[a][3][1]));
      float m2 = fmaxf(fmaxf(st[a][0][2], st[a][1][2]), fmaxf(st[a][2][2], st[a][3][2]));
      float m3 = fmaxf(fmaxf(st[a][0][3], st[a][1][3]), fmaxf(st[a][2][3], st[a][3][3]));
      float mx = fmaxf(fmaxf(m0, m1), fmaxf(m2, m3));
      mx = fmaxf(mx, __shfl_xor(mx, 16));
      mx = fmaxf(mx, __shfl_xor(mx, 32));
      pm[a] = mx * SC;
    }
  };
  auto rescale1 = [&](float(&pm)[2], float(&mrun)[2], f32x4(&ls)[2], f32x4(&o)[2][4]) {
#pragma unroll
    for (int a = 0; a < 2; ++a) {
      float mnew = fmaxf(mrun[a], pm[a]);
      float sc = exp2f(mrun[a] - mnew);
      mrun[a] = mnew;
#pragma unroll
      for (int r = 0; r < 4; ++r) {
        float sco = __shfl(sc, (lane & 48) | (lk * 4 + r));
        ls[a][r] *= sco;
#pragma unroll
        for (int nd = 0; nd < 4; ++nd) o[a][nd][r] *= sco;
      }
    }
  };
  auto pack = [&](f32x4(&st)[2][4], float(&mrun)[2], char* buf, int rb) {
#pragma unroll
    for (int a = 0; a < 2; ++a)
#pragma unroll
      for (int n = 0; n < 4; ++n) {
        float2 p01, p23;
        p01.x = exp2f(fmaf(st[a][n][0], SC, -mrun[a]));
        p01.y = exp2f(fmaf(st[a][n][1], SC, -mrun[a]));
        p23.x = exp2f(fmaf(st[a][n][2], SC, -mrun[a]));
        p23.y = exp2f(fmaf(st[a][n][3], SC, -mrun[a]));
        __hip_bfloat162 b01 = __float22bfloat162_rn(p01);
        __hip_bfloat162 b23 = __float22bfloat162_rn(p23);
        uint2 w;
        w.x = *(unsigned*)&b01;
        w.y = *(unsigned*)&b23;
        *(uint2*)(buf + (rb + a * 16 + lr) * 144 + n * 32 + lk * 8) = w;
      }
  };
  auto pv = [&](char* buf, short8(&v)[2][4]) {
#pragma unroll
    for (int kb = 0; kb < 2; ++kb) {
      short8 pfA0 = *(const short8*)(buf + (0 + lr) * 144 + kb * 64 + lk * 16);
      short8 pfA1 = *(const short8*)(buf + (16 + lr) * 144 + kb * 64 + lk * 16);
      short8 pfB0 = *(const short8*)(buf + (32 + lr) * 144 + kb * 64 + lk * 16);
      short8 pfB1 = *(const short8*)(buf + (48 + lr) * 144 + kb * 64 + lk * 16);
#pragma unroll
      for (int nd = 0; nd < 4; ++nd) {
        oA[0][nd] = MFMA_BF16(pfA0, v[kb][nd], oA[0][nd]);
        oA[1][nd] = MFMA_BF16(pfA1, v[kb][nd], oA[1][nd]);
        oB[0][nd] = MFMA_BF16(pfB0, v[kb][nd], oB[0][nd]);
        oB[1][nd] = MFMA_BF16(pfB1, v[kb][nd], oB[1][nd]);
      }
      lsA[0] = MFMA_BF16(pfA0, vones, lsA[0]);
      lsA[1] = MFMA_BF16(pfA1, vones, lsA[1]);
      lsB[0] = MFMA_BF16(pfB0, vones, lsB[0]);
      lsB[1] = MFMA_BF16(pfB1, vones, lsB[1]);
    }
  };

  // per-tile body: QK(i) + rowmax + [PV(i-1)] + rescale + pack(i)
  auto tile = [&](int i, bool diag, bool doPV,
                  short8(&kfc)[2][4], short8(&kfn)[2][4],
                  short8(&vp)[2][4], short8(&vc)[2][4],
                  char* bufp, char* bufc, int tnext) {
    loadK(kfn, tnext);
    loadV(vc, i);
    f32x4 stA[2][4] = {}, stB[2][4] = {};
#pragma unroll
    for (int kb = 0; kb < 2; ++kb)
#pragma unroll
      for (int a = 0; a < 2; ++a)
#pragma unroll
        for (int n = 0; n < 4; ++n) {
          stA[a][n] = MFMA_BF16(kfc[kb][n], qfA[a][kb], stA[a][n]);
          stB[a][n] = MFMA_BF16(kfc[kb][n], qfB[a][kb], stB[a][n]);
        }
    if (diag) {
#pragma unroll
      for (int a = 0; a < 2; ++a)
#pragma unroll
        for (int n = 0; n < 4; ++n)
#pragma unroll
          for (int r = 0; r < 4; ++r) {
            if (n * 16 + lk * 4 + r > 0 + a * 16 + lr) stA[a][n][r] = -3e38f;
            if (n * 16 + lk * 4 + r > 32 + a * 16 + lr) stB[a][n][r] = -3e38f;
          }
    }
    float pmA[2], pmB[2];
    rowmax(stA, pmA);
    rowmax(stB, pmB);
    float need = fmaxf(fmaxf(pmA[0] - mA[0], pmA[1] - mA[1]),
                       fmaxf(pmB[0] - mB[0], pmB[1] - mB[1]));
    if (doPV) pv(bufp, vp);  // absorbs tile i-1 at OLD scale (before rescale)
    if (__any(need > 8.f)) {
      rescale1(pmA, mA, lsA, oA);
      rescale1(pmB, mB, lsB, oB);
    }
    pack(stA, mA, bufc, 0);
    pack(stB, mB, bufc, 32);
  };

  short8 kf0[2][4], kf1[2][4], v0[2][4], v1[2][4];

  // prologue: tile 0 (no PV), K(1) prefetched
  loadK(kf0, 0);
  tile(0, nt == 1, false, kf0, kf1, v1, v0, bufB, bufA, (1 < nt) ? 1 : 0);

  int i = 1;
  while (i < nt) {
    tile(i, i == nt - 1, true, kf1, kf0, v0, v1, bufA, bufB, (i + 1 < nt) ? i + 1 : i);
    if (++i >= nt) break;
    tile(i, i == nt - 1, true, kf0, kf1, v1, v0, bufB, bufA, (i + 1 < nt) ? i + 1 : i);
    ++i;
  }
  // epilogue: PV of last tile
  if ((nt - 1) & 1) pv(bufB, v1);
  else              pv(bufA, v0);

  const int b = bh >> 4, h2 = bh & 15;
#pragma unroll
  for (int a = 0; a < 2; ++a)
#pragma unroll
    for (int r = 0; r < 4; ++r) {
      float invA = 1.0f / lsA[a][r];
      float invB = 1.0f / lsB[a][r];
      int tA = q0 + a * 16 + lk * 4 + r;
      int tB = tA + 32;
#pragma unroll
      for (int nd = 0; nd < 4; ++nd) {
        ctx[((size_t)b * T_ + tA) * E_ + h2 * D_ + nd * 16 + lr] = f2bf(oA[a][nd][r] * invA);
        ctx[((size_t)b * T_ + tB) * E_ + h2 * D_ + nd * 16 + lr] = f2bf(oB[a][nd][r] * invB);
      }
    }
}

// ---------------- launcher ----------------
extern "C" void kernel_launch(void* const* d_in, const int* in_sizes, int n_in,
                              void* d_out, int out_size, void* d_ws, size_t ws_size,
                              hipStream_t stream) {
  const float* x    = (const float*)d_in[0];
  const float* Wq   = (const float*)d_in[1];
  const float* Wk   = (const float*)d_in[2];
  const float* Wv   = (const float*)d_in[3];
  const float* Wout = (const float*)d_in[4];
  const float* bout = (const float*)d_in[5];
  float* out = (float*)d_out;

  const size_t MT = (size_t)B_ * T_;      // 8192
  const size_t XE = MT * E_;              // 8,388,608
  const size_t WE = (size_t)E_ * E_;      // 1,048,576

  size_t need = (XE * 5 + WE * 4) * sizeof(unsigned short);
  if (ws_size < need) return;

  unsigned short* xb  = (unsigned short*)d_ws;
  unsigned short* wqb = xb + XE;
  unsigned short* wkb = wqb + WE;
  unsigned short* wvb = wkb + WE;
  unsigned short* wob = wvb + WE;
  unsigned short* Qb  = wob + WE;
  unsigned short* Kb  = Qb + XE;
  unsigned short* VTb = Kb + XE;
  unsigned short* ctx = VTb + XE;

  cvt_f32_bf16<<<(int)(XE / 8 / 256), 256, 0, stream>>>(x, xb, (int)(XE / 8));
  cvt_w4<<<2048, 256, 0, stream>>>(Wq, Wk, Wv, Wout, wqb);

  gemm_qkv<<<dim3(MT / 128, 24), 256, 0, stream>>>(xb, wqb, wkb, wvb, Qb, Kb, VTb);  // V written transposed

  attn_fused<<<2048, 64, 0, stream>>>(Qb, Kb, VTb, ctx);

  gemm_out<<<dim3(MT / 128, E_ / 128), 256, 0, stream>>>(ctx, wob, out, bout, (int)MT, E_, E_);
}